// Round 1
// baseline (256.521 us; speedup 1.0000x reference)
//
#include <hip/hip_runtime.h>
#include <hip/hip_bf16.h>
#include <stdint.h>

#define M_DIM 8192
#define N_DIM 4096
#define K_DIM 4096

#define BM 128
#define BN 128
#define BK 64                 // 64 int8 along K per step = one mfma_i32_16x16x64_i8
#define NT (K_DIM / BK)       // 64 K-steps

typedef int v4i __attribute__((ext_vector_type(4)));

#define AS1C(p) ((const __attribute__((address_space(1))) void*)(p))
#define AS3(p)  ((__attribute__((address_space(3))) void*)(p))

// ---------------------------------------------------------------------------
// Pack pass: int32 (int8-range) -> int8.  16 ints -> 16 bytes per chunk.
// Memory-bound; vectorized int4 loads / int4 stores.
// ---------------------------------------------------------------------------
__device__ __forceinline__ int pack4(int a, int b, int c, int d) {
  return (a & 0xff) | ((b & 0xff) << 8) | ((c & 0xff) << 16) | (d << 24);
}

__global__ void pack_i8_kernel(const int* __restrict__ in, char* __restrict__ out,
                               int nchunks) {
  int idx = blockIdx.x * blockDim.x + threadIdx.x;
  int stride = gridDim.x * blockDim.x;
  const int4* pin = (const int4*)in;
  int4* pout = (int4*)out;
  for (int i = idx; i < nchunks; i += stride) {
    int4 v0 = pin[4 * i + 0];
    int4 v1 = pin[4 * i + 1];
    int4 v2 = pin[4 * i + 2];
    int4 v3 = pin[4 * i + 3];
    int4 o;
    o.x = pack4(v0.x, v0.y, v0.z, v0.w);
    o.y = pack4(v1.x, v1.y, v1.z, v1.w);
    o.z = pack4(v2.x, v2.y, v2.z, v2.w);
    o.w = pack4(v3.x, v3.y, v3.z, v3.w);
    pout[i] = o;
  }
}

// ---------------------------------------------------------------------------
// int8 GEMM, m97 structure: 128x128 tile, 4 waves (2x2) each owning 64x64,
// BK=64 bytes, global_load_lds(16B) staging, double-buffered LDS.
// A = x[M,K] row-major int8; B = weight[N,K] row-major int8 (NT-gemm).
// acc[m][n] = sum_k A[m][k]*B[n][k]; epilogue rintf(alpha*acc + beta*bias[n]).
//
// LDS swizzle (both-sides, rule #21): row stride is 64B; physical 16B chunk
// p holds global chunk g = p ^ ((row>>1)&3).  Reader XORs the same way ->
// 2-way bank aliasing only (free).
// ---------------------------------------------------------------------------
__global__ __launch_bounds__(256) void gemm_i8_kernel(
    const char* __restrict__ A8, const char* __restrict__ B8,
    const int* __restrict__ bias, const float* __restrict__ alpha_p,
    const float* __restrict__ beta_p, int* __restrict__ out) {
  __shared__ alignas(16) char As[2][BM * BK];   // 8 KiB each buffer
  __shared__ alignas(16) char Bs[2][BN * BK];

  const int tid  = threadIdx.x;
  const int lane = tid & 63;
  const int wave = tid >> 6;

  const int bm = blockIdx.y * BM;
  const int bn = blockIdx.x * BN;

  // Staging geometry: tile = 8192B = 4 waves x 2 rounds x 1024B (lane x 16B).
  int aoff[2], boff[2], ldsoff[2];
#pragma unroll
  for (int i = 0; i < 2; ++i) {
    int linear = (wave + i * 4) * 1024 + lane * 16;
    int row = linear >> 6;            // LDS row (64B rows)
    int p   = (linear >> 4) & 3;      // physical 16B chunk within row
    int g   = p ^ ((row >> 1) & 3);   // pre-swizzled global chunk
    ldsoff[i] = (wave + i * 4) * 1024;         // wave-uniform LDS base
    aoff[i] = (bm + row) * K_DIM + g * 16;     // per-lane global offset
    boff[i] = (bn + row) * K_DIM + g * 16;
  }

  v4i acc[4][4];
#pragma unroll
  for (int i = 0; i < 4; ++i)
#pragma unroll
    for (int j = 0; j < 4; ++j) acc[i][j] = (v4i){0, 0, 0, 0};

  const int wr = (wave >> 1) * 64;  // wave's row offset in tile
  const int wc = (wave & 1) * 64;   // wave's col offset in tile
  const int frow = lane & 15;       // fragment row/col within 16x16
  const int fchunk = lane >> 4;     // which 16B K-chunk this lane reads

  // prologue stage of buffer 0
  {
    const char* ab = A8;
    const char* bb = B8;
#pragma unroll
    for (int i = 0; i < 2; ++i) {
      __builtin_amdgcn_global_load_lds(AS1C(ab + aoff[i]), AS3(&As[0][ldsoff[i]]), 16, 0, 0);
      __builtin_amdgcn_global_load_lds(AS1C(bb + boff[i]), AS3(&Bs[0][ldsoff[i]]), 16, 0, 0);
    }
  }

  int cur = 0;
  for (int kt = 0; kt < NT; ++kt) {
    __syncthreads();  // staging of 'cur' complete (compiler drains vmcnt here)

    if (kt + 1 < NT) {
      const char* ab = A8 + (kt + 1) * BK;
      const char* bb = B8 + (kt + 1) * BK;
      int nb = cur ^ 1;
#pragma unroll
      for (int i = 0; i < 2; ++i) {
        __builtin_amdgcn_global_load_lds(AS1C(ab + aoff[i]), AS3(&As[nb][ldsoff[i]]), 16, 0, 0);
        __builtin_amdgcn_global_load_lds(AS1C(bb + boff[i]), AS3(&Bs[nb][ldsoff[i]]), 16, 0, 0);
      }
    }

    v4i af[4], bf[4];
#pragma unroll
    for (int mi = 0; mi < 4; ++mi) {
      int r = wr + mi * 16 + frow;
      af[mi] = *(const v4i*)&As[cur][r * 64 + ((fchunk ^ ((r >> 1) & 3)) << 4)];
    }
#pragma unroll
    for (int nj = 0; nj < 4; ++nj) {
      int r = wc + nj * 16 + frow;
      bf[nj] = *(const v4i*)&Bs[cur][r * 64 + ((fchunk ^ ((r >> 1) & 3)) << 4)];
    }

#pragma unroll
    for (int mi = 0; mi < 4; ++mi)
#pragma unroll
      for (int nj = 0; nj < 4; ++nj)
        acc[mi][nj] = __builtin_amdgcn_mfma_i32_16x16x64_i8(af[mi], bf[nj], acc[mi][nj], 0, 0, 0);

    cur ^= 1;
  }

  // Epilogue: D = rint(alpha*acc + beta*bias[n]) as int32.
  // C/D layout: col = lane&15, row = (lane>>4)*4 + reg.
  const float alpha = *alpha_p;
  const float beta  = *beta_p;
  const int col0 = bn + wc + frow;
  float bb4[4];
#pragma unroll
  for (int nj = 0; nj < 4; ++nj) bb4[nj] = beta * (float)bias[col0 + nj * 16];

  const int rbase = bm + wr + (lane >> 4) * 4;
#pragma unroll
  for (int mi = 0; mi < 4; ++mi) {
#pragma unroll
    for (int r = 0; r < 4; ++r) {
      size_t rowoff = (size_t)(rbase + mi * 16 + r) * N_DIM;
#pragma unroll
      for (int nj = 0; nj < 4; ++nj) {
        out[rowoff + col0 + nj * 16] =
            (int)rintf(fmaf(alpha, (float)acc[mi][nj][r], bb4[nj]));
      }
    }
  }
}

// ---------------------------------------------------------------------------
// Safety fallback if ws is too small for the packed operands (slow but right).
// ---------------------------------------------------------------------------
__global__ void naive_kernel(const int* __restrict__ x, const int* __restrict__ w,
                             const int* __restrict__ bias,
                             const float* __restrict__ alpha_p,
                             const float* __restrict__ beta_p,
                             int* __restrict__ out) {
  size_t idx = (size_t)blockIdx.x * 256 + threadIdx.x;
  int m = (int)(idx / N_DIM);
  int n = (int)(idx % N_DIM);
  const int4* xr = (const int4*)(x + (size_t)m * K_DIM);
  const int4* wr = (const int4*)(w + (size_t)n * K_DIM);
  int acc = 0;
  for (int k = 0; k < K_DIM / 4; ++k) {
    int4 a = xr[k];
    int4 b = wr[k];
    acc += a.x * b.x + a.y * b.y + a.z * b.z + a.w * b.w;
  }
  out[idx] = (int)rintf(fmaf(*alpha_p, (float)acc, (*beta_p) * (float)bias[n]));
}

extern "C" void kernel_launch(void* const* d_in, const int* in_sizes, int n_in,
                              void* d_out, int out_size, void* d_ws, size_t ws_size,
                              hipStream_t stream) {
  const int*   x     = (const int*)d_in[0];
  const int*   w     = (const int*)d_in[1];
  const int*   bias  = (const int*)d_in[2];
  const float* alpha = (const float*)d_in[3];
  const float* beta  = (const float*)d_in[4];
  int* out = (int*)d_out;

  const size_t a8_bytes = (size_t)M_DIM * K_DIM;  // 32 MiB
  const size_t b8_bytes = (size_t)N_DIM * K_DIM;  // 16 MiB

  if (ws_size >= a8_bytes + b8_bytes) {
    char* A8 = (char*)d_ws;
    char* B8 = A8 + a8_bytes;
    pack_i8_kernel<<<2048, 256, 0, stream>>>(x, A8, (int)(a8_bytes / 16));
    pack_i8_kernel<<<2048, 256, 0, stream>>>(w, B8, (int)(b8_bytes / 16));
    dim3 grid(N_DIM / BN, M_DIM / BM);
    gemm_i8_kernel<<<grid, 256, 0, stream>>>(A8, B8, bias, alpha, beta, out);
  } else {
    naive_kernel<<<(M_DIM * (size_t)N_DIM) / 256, 256, 0, stream>>>(x, w, bias, alpha, beta, out);
  }
}

// Round 2
// 186.244 us; speedup vs baseline: 1.3773x; 1.3773x over previous
//
#include <hip/hip_runtime.h>
#include <hip/hip_bf16.h>
#include <stdint.h>

#define M_DIM 8192
#define N_DIM 4096
#define K_DIM 4096

#define BM 256
#define BN 256
#define BK 64                 // bytes of K per pipeline stage = one mfma_i32_16x16x64_i8 K
#define NT (K_DIM / BK)       // 64 K-tiles
#define DEPTH 4               // circular LDS pipeline depth

typedef int v4i __attribute__((ext_vector_type(4)));

#define AS1C(p) ((const __attribute__((address_space(1))) void*)(p))
#define AS3(p)  ((__attribute__((address_space(3))) void*)(p))

// ---------------------------------------------------------------------------
// Pack pass: int32 (int8-range) -> int8.  16 ints -> 16 bytes per chunk.
// ---------------------------------------------------------------------------
__device__ __forceinline__ int pack4(int a, int b, int c, int d) {
  return (a & 0xff) | ((b & 0xff) << 8) | ((c & 0xff) << 16) | (d << 24);
}

__global__ void pack_i8_kernel(const int* __restrict__ in, char* __restrict__ out,
                               int nchunks) {
  int idx = blockIdx.x * blockDim.x + threadIdx.x;
  int stride = gridDim.x * blockDim.x;
  const int4* pin = (const int4*)in;
  int4* pout = (int4*)out;
  for (int i = idx; i < nchunks; i += stride) {
    int4 v0 = pin[4 * i + 0];
    int4 v1 = pin[4 * i + 1];
    int4 v2 = pin[4 * i + 2];
    int4 v3 = pin[4 * i + 3];
    int4 o;
    o.x = pack4(v0.x, v0.y, v0.z, v0.w);
    o.y = pack4(v1.x, v1.y, v1.z, v1.w);
    o.z = pack4(v2.x, v2.y, v2.z, v2.w);
    o.w = pack4(v3.x, v3.y, v3.z, v3.w);
    pout[i] = o;
  }
}

// ---------------------------------------------------------------------------
// int8 GEMM, 256x256 tile, 8 waves (2Mx4N, per-wave 128x64), BK=64B,
// 4-deep LDS circular pipeline with counted vmcnt (T3+T4), raw s_barrier,
// setprio around the MFMA cluster (T5), XCD-aware block swizzle (T1),
// conflict-free chunk-XOR LDS swizzle (verified 0 conflicts in R1).
//
// Pipeline invariants (1 barrier / K-tile):
//   loop top, iter t: own loads outstanding = tiles t..t+2 (<=12).
//   s_waitcnt vmcnt(8)  -> tile t's 4 loads complete (2 tiles x 4 behind it).
//   + lgkmcnt(0)        -> own ds_reads of compute(t-1) drained.
//   s_barrier           -> ALL waves: tile-t staged, compute(t-1) reads done.
//   STAGE(t+3)          -> overwrites buf[(t-1)&3]; safe per the barrier.
//   COMPUTE(t)          -> 12 ds_read_b128 + 32 MFMA (compiler-scheduled).
// Last two tiles peeled with vmcnt(4) / vmcnt(0).
// ---------------------------------------------------------------------------
__global__ __launch_bounds__(512, 2) void gemm_i8_kernel(
    const char* __restrict__ A8, const char* __restrict__ B8,
    const int* __restrict__ bias, const float* __restrict__ alpha_p,
    const float* __restrict__ beta_p, int* __restrict__ out) {
  __shared__ alignas(16) char lds[DEPTH][BM * BK + BN * BK];  // 4 x 32 KiB = 128 KiB

  const int tid  = threadIdx.x;
  const int lane = tid & 63;
  const int wave = tid >> 6;

  // XCD-aware bijective swizzle: 512 blocks, 64 consecutive per XCD.
  const int orig = blockIdx.x;
  const int swz  = (orig & 7) * (512 / 8) + (orig >> 3);
  const int bm   = (swz >> 4) * BM;  // 32 row-tiles
  const int bn   = (swz & 15) * BN;  // 16 col-tiles

  // Staging geometry: per operand tile 16 KB = 2 rounds x 512 thr x 16 B.
  // Pre-swizzled global chunk g = p ^ ((row>>1)&3) (both-sides swizzle).
  int aoff[2], boff[2], ldsoff[2];
#pragma unroll
  for (int i = 0; i < 2; ++i) {
    int linear = i * 8192 + tid * 16;
    int row = linear >> 6;           // 64 B rows
    int p   = (linear >> 4) & 3;
    int g   = p ^ ((row >> 1) & 3);
    ldsoff[i] = i * 8192 + wave * 1024;       // wave-uniform LDS base
    aoff[i] = (bm + row) * K_DIM + g * 16;
    boff[i] = (bn + row) * K_DIM + g * 16;
  }

#define STAGE(t)                                                                    \
  do {                                                                              \
    const char* ab_ = A8 + (t) * BK;                                                \
    const char* bb_ = B8 + (t) * BK;                                                \
    char* base_ = &lds[(t) & (DEPTH - 1)][0];                                       \
    _Pragma("unroll") for (int i_ = 0; i_ < 2; ++i_) {                              \
      __builtin_amdgcn_global_load_lds(AS1C(ab_ + aoff[i_]),                        \
                                       AS3(base_ + ldsoff[i_]), 16, 0, 0);          \
      __builtin_amdgcn_global_load_lds(AS1C(bb_ + boff[i_]),                        \
                                       AS3(base_ + 16384 + ldsoff[i_]), 16, 0, 0);  \
    }                                                                               \
  } while (0)

  v4i acc[8][4];
#pragma unroll
  for (int i = 0; i < 8; ++i)
#pragma unroll
    for (int j = 0; j < 4; ++j) acc[i][j] = (v4i){0, 0, 0, 0};

  const int wr = wave >> 2;         // 0..1 (M half)
  const int wc = wave & 3;          // 0..3 (N quarter)
  const int frow = lane & 15;
  // swizzle XOR depends only on frow (rows differ by multiples of 16) -> lane-const
  const int swzoff = ((lane >> 4) ^ ((frow >> 1) & 3)) << 4;

#define COMPUTE(t)                                                                  \
  do {                                                                              \
    const char* base_ = &lds[(t) & (DEPTH - 1)][0];                                 \
    const char* As_ = base_;                                                        \
    const char* Bs_ = base_ + 16384;                                                \
    v4i bf[4];                                                                      \
    _Pragma("unroll") for (int nj = 0; nj < 4; ++nj) {                              \
      int r_ = wc * 64 + nj * 16 + frow;                                            \
      bf[nj] = *(const v4i*)(Bs_ + r_ * 64 + swzoff);                               \
    }                                                                               \
    __builtin_amdgcn_s_setprio(1);                                                  \
    _Pragma("unroll") for (int mi = 0; mi < 8; ++mi) {                              \
      int r_ = wr * 128 + mi * 16 + frow;                                           \
      v4i af_ = *(const v4i*)(As_ + r_ * 64 + swzoff);                              \
      _Pragma("unroll") for (int nj = 0; nj < 4; ++nj)                              \
        acc[mi][nj] = __builtin_amdgcn_mfma_i32_16x16x64_i8(af_, bf[nj],            \
                                                            acc[mi][nj], 0, 0, 0); \
    }                                                                               \
    __builtin_amdgcn_s_setprio(0);                                                  \
  } while (0)

  // Prologue: fill 3 pipeline stages.
  STAGE(0);
  STAGE(1);
  STAGE(2);

  for (int t = 0; t < NT - 2; ++t) {
    asm volatile("s_waitcnt vmcnt(8) lgkmcnt(0)" ::: "memory");
    __builtin_amdgcn_s_barrier();
    if (t + 3 < NT) STAGE(t + 3);
    COMPUTE(t);
  }
  asm volatile("s_waitcnt vmcnt(4) lgkmcnt(0)" ::: "memory");
  __builtin_amdgcn_s_barrier();
  COMPUTE(NT - 2);
  asm volatile("s_waitcnt vmcnt(0) lgkmcnt(0)" ::: "memory");
  __builtin_amdgcn_s_barrier();
  COMPUTE(NT - 1);

  // Epilogue: D = rint(alpha*acc + beta*bias[n]).
  // C/D layout (16x16): col = lane&15, row = (lane>>4)*4 + reg.
  const float alpha = *alpha_p;
  const float beta  = *beta_p;
  const int col0 = bn + wc * 64 + frow;
  float bb4[4];
#pragma unroll
  for (int nj = 0; nj < 4; ++nj) bb4[nj] = beta * (float)bias[col0 + nj * 16];

  const int rbase = bm + wr * 128 + (lane >> 4) * 4;
#pragma unroll
  for (int mi = 0; mi < 8; ++mi) {
#pragma unroll
    for (int r = 0; r < 4; ++r) {
      size_t rowoff = (size_t)(rbase + mi * 16 + r) * N_DIM;
#pragma unroll
      for (int nj = 0; nj < 4; ++nj) {
        out[rowoff + col0 + nj * 16] =
            (int)rintf(fmaf(alpha, (float)acc[mi][nj][r], bb4[nj]));
      }
    }
  }
#undef STAGE
#undef COMPUTE
}

// ---------------------------------------------------------------------------
// Safety fallback if ws is too small for the packed operands (slow but right).
// ---------------------------------------------------------------------------
__global__ void naive_kernel(const int* __restrict__ x, const int* __restrict__ w,
                             const int* __restrict__ bias,
                             const float* __restrict__ alpha_p,
                             const float* __restrict__ beta_p,
                             int* __restrict__ out) {
  size_t idx = (size_t)blockIdx.x * 256 + threadIdx.x;
  int m = (int)(idx / N_DIM);
  int n = (int)(idx % N_DIM);
  const int4* xr = (const int4*)(x + (size_t)m * K_DIM);
  const int4* wr = (const int4*)(w + (size_t)n * K_DIM);
  int acc = 0;
  for (int k = 0; k < K_DIM / 4; ++k) {
    int4 a = xr[k];
    int4 b = wr[k];
    acc += a.x * b.x + a.y * b.y + a.z * b.z + a.w * b.w;
  }
  out[idx] = (int)rintf(fmaf(*alpha_p, (float)acc, (*beta_p) * (float)bias[n]));
}

extern "C" void kernel_launch(void* const* d_in, const int* in_sizes, int n_in,
                              void* d_out, int out_size, void* d_ws, size_t ws_size,
                              hipStream_t stream) {
  const int*   x     = (const int*)d_in[0];
  const int*   w     = (const int*)d_in[1];
  const int*   bias  = (const int*)d_in[2];
  const float* alpha = (const float*)d_in[3];
  const float* beta  = (const float*)d_in[4];
  int* out = (int*)d_out;

  const size_t a8_bytes = (size_t)M_DIM * K_DIM;  // 32 MiB
  const size_t b8_bytes = (size_t)N_DIM * K_DIM;  // 16 MiB

  if (ws_size >= a8_bytes + b8_bytes) {
    char* A8 = (char*)d_ws;
    char* B8 = A8 + a8_bytes;
    pack_i8_kernel<<<2048, 256, 0, stream>>>(x, A8, (int)(a8_bytes / 16));
    pack_i8_kernel<<<2048, 256, 0, stream>>>(w, B8, (int)(b8_bytes / 16));
    const int nblk = (M_DIM / BM) * (N_DIM / BN);  // 32*16 = 512
    gemm_i8_kernel<<<nblk, 512, 0, stream>>>(A8, B8, bias, alpha, beta, out);
  } else {
    naive_kernel<<<(M_DIM * (size_t)N_DIM) / 256, 256, 0, stream>>>(x, w, bias, alpha, beta, out);
  }
}